// Round 13
// baseline (63.481 us; speedup 1.0000x reference)
//
#include <hip/hip_runtime.h>
#include <stdint.h>

// B=1, N=2048, D=1024, h=16, e=64; chunks of 64 tokens -> 32 chunks/head
#define NTOK 2048
#define NCH 32

typedef __attribute__((ext_vector_type(8))) short bf16x8;
typedef __attribute__((ext_vector_type(8))) unsigned short ushort8v;
typedef __attribute__((ext_vector_type(4))) float f32x4;

__device__ __forceinline__ unsigned short f2bf(float f) {
  unsigned u = __float_as_uint(f);
  u += 0x7fffu + ((u >> 16) & 1u);   // RNE
  return (unsigned short)(u >> 16);
}
__device__ __forceinline__ float bf2f(unsigned short s) {
  return __uint_as_float(((unsigned)s) << 16);
}

// ---- fused input prep: x -> bf16 (blocks 0..2047), W -> Wt bf16 transposed (blocks 2048..5119) ----
__global__ __launch_bounds__(256) void k_prep_inputs(const float* __restrict__ x,
                                                     unsigned short* __restrict__ xb,
                                                     const float* __restrict__ W,
                                                     unsigned short* __restrict__ Wt) {
  int bid = blockIdx.x;
  if (bid < 2048) {
    int i = (bid * 256 + threadIdx.x) * 4;
    float4 v = *(const float4*)(x + i);
    ushort4 o = { f2bf(v.x), f2bf(v.y), f2bf(v.z), f2bf(v.w) };
    *(ushort4*)(xb + i) = o;
  } else {
    __shared__ float tile[32][33];
    int id = bid - 2048;            // 3072 blocks: bx in [0,96), by in [0,32)
    int bx = id % 96, by = id / 96;
    int tx = threadIdx.x & 31, ty = threadIdx.x >> 5;
    int c0 = bx * 32;
    int r0 = by * 32;
#pragma unroll
    for (int j = 0; j < 32; j += 8)
      tile[ty + j][tx] = W[(size_t)(r0 + ty + j) * 3072 + c0 + tx];
    __syncthreads();
#pragma unroll
    for (int j = 0; j < 32; j += 8)
      Wt[(size_t)(c0 + ty + j) * 1024 + r0 + tx] = f2bf(tile[tx][ty + j]);
  }
}

// ---- GEMM 2048x3072, 128x192 tile, 768 thr (12 waves of 32x64), BK=64 ----
// R12 geometry (1 block/CU) + R8 counted-vmcnt schedule. k-region epilogue now
// also accumulates per-chunk z[d] = sum_tok exp(k) via 2 deterministic f32 atomics.
__global__ __launch_bounds__(768, 1) void k_gemm_fused(const unsigned short* __restrict__ xb,
                                                       const unsigned short* __restrict__ wt,
                                                       const float* __restrict__ bias,
                                                       unsigned short* __restrict__ qh,
                                                       unsigned short* __restrict__ kh,
                                                       unsigned short* __restrict__ kt,
                                                       unsigned short* __restrict__ vt,
                                                       float* __restrict__ zc) {
  __shared__ __align__(16) unsigned short As[2][128][64];    // 2 x 16 KB
  __shared__ __align__(16) unsigned short Bs[2][192][64];    // 2 x 24 KB
  const int t = threadIdx.x;           // 0..767
  const int lane = t & 63;
  const int wave = t >> 6;             // 0..11
  const int wr = wave / 3;             // 0..3 (32-row block)
  const int wc = wave % 3;             // 0..2 (64-col block)
  const int rowBase = blockIdx.y * 128;
  const int colBase = blockIdx.x * 192;
  const int fr = lane & 15;
  const int khalf = lane >> 4;         // 0..3

  // staging: A = 1024 chunks over threads 0..255 (4 each); B = 1536 over 256..767 (3 each)
  const bool isA = t < 256;            // wave-uniform (boundary at wave 4)
  const int nL = isA ? 4 : 3;
  const int bstr = isA ? 16384 : 24576;
  const unsigned short* gsrc[4];
  char* ldst[4];
#pragma unroll
  for (int j = 0; j < 4; ++j) {
    int idx = isA ? (t + j * 256) : (t - 256 + j * 512);
    if (j >= nL) idx = 0;              // dummy, never issued
    int row = idx >> 3;
    int ssl = (idx & 7) ^ (row & 7);   // XOR swizzle (inverse on source)
    gsrc[j] = (isA ? xb + (size_t)(rowBase + row) * 1024
                   : wt + (size_t)(colBase + row) * 1024) + ssl * 8;
    ldst[j] = (isA ? (char*)As : (char*)Bs) + idx * 16;
  }

#define STG(buf, kt0) do {                                                                \
    _Pragma("unroll")                                                                     \
    for (int j_ = 0; j_ < 4; ++j_)                                                        \
      if (j_ < nL)                                                                        \
        __builtin_amdgcn_global_load_lds(                                                 \
            (const __attribute__((address_space(1))) void*)(gsrc[j_] + (kt0) * 64),       \
            (__attribute__((address_space(3))) void*)(ldst[j_] + (buf) * bstr), 16, 0, 0);\
  } while (0)

#define VMW_STEADY() do {                                                                 \
    if (isA) asm volatile("s_waitcnt vmcnt(4)" ::: "memory");                             \
    else     asm volatile("s_waitcnt vmcnt(3)" ::: "memory");                             \
  } while (0)
#define VMCNT0() asm volatile("s_waitcnt vmcnt(0)" ::: "memory")
#define LGKM0()  asm volatile("s_waitcnt lgkmcnt(0)" ::: "memory")
#define BAR()    __builtin_amdgcn_s_barrier()

  f32x4 acc[2][4] = {};
  const int fs0 = khalf ^ (fr & 7);   // swizzled slot for ks=0; ks=1 is fs0^4

#define LOAD_FRAGS(cur, af, bff) do {                                                     \
    _Pragma("unroll")                                                                     \
    for (int m = 0; m < 2; ++m) {                                                         \
      const unsigned short* r = &As[cur][wr * 32 + m * 16 + fr][0];                       \
      af[m][0] = *(const bf16x8*)(r + fs0 * 8);                                           \
      af[m][1] = *(const bf16x8*)(r + (fs0 ^ 4) * 8);                                     \
    }                                                                                     \
    _Pragma("unroll")                                                                     \
    for (int n = 0; n < 4; ++n) {                                                         \
      const unsigned short* r = &Bs[cur][wc * 64 + n * 16 + fr][0];                       \
      bff[n][0] = *(const bf16x8*)(r + fs0 * 8);                                          \
      bff[n][1] = *(const bf16x8*)(r + (fs0 ^ 4) * 8);                                    \
    }                                                                                     \
  } while (0)

#define DO_MFMA(af, bff) do {                                                             \
    _Pragma("unroll")                                                                     \
    for (int m = 0; m < 2; ++m)                                                           \
      _Pragma("unroll")                                                                   \
      for (int n = 0; n < 4; ++n) {                                                       \
        acc[m][n] = __builtin_amdgcn_mfma_f32_16x16x32_bf16(af[m][0], bff[n][0], acc[m][n], 0, 0, 0); \
        acc[m][n] = __builtin_amdgcn_mfma_f32_16x16x32_bf16(af[m][1], bff[n][1], acc[m][n], 0, 0, 0); \
      }                                                                                   \
  } while (0)

  STG(0, 0);
  STG(1, 1);
#pragma unroll 1
  for (int ktile = 0; ktile < 14; ++ktile) {
    const int cur = ktile & 1;
    VMW_STEADY();
    BAR();
    bf16x8 af[2][2], bff[4][2];
    LOAD_FRAGS(cur, af, bff);
    LGKM0();
    __builtin_amdgcn_sched_barrier(0);
    BAR();
    STG(cur, ktile + 2);
    __builtin_amdgcn_s_setprio(1);
    DO_MFMA(af, bff);
    __builtin_amdgcn_s_setprio(0);
  }
  {
    VMW_STEADY();
    BAR();
    bf16x8 af[2][2], bff[4][2];
    LOAD_FRAGS(0, af, bff);
    DO_MFMA(af, bff);
  }
  {
    VMCNT0();
    BAR();
    bf16x8 af[2][2], bff[4][2];
    LOAD_FRAGS(1, af, bff);
    DO_MFMA(af, bff);
  }
#undef STG
#undef LOAD_FRAGS
#undef DO_MFMA

  // ---- fused epilogue (per wave: 32 rows x one 64-col head span) ----
  const int g2 = khalf;
  const int ocol = lane & 15;
  const int col0 = colBase + wc * 64;
  const int region = col0 >> 10;      // 0=q 1=v 2=k
  const int h = (col0 & 1023) >> 6;
  const int r0 = rowBase + wr * 32;
  const int cch = r0 >> 6;
  const int lbase = (wr & 1) * 32;
  float bv[4];
#pragma unroll
  for (int n = 0; n < 4; ++n) bv[n] = bias[col0 + 16 * n + ocol];

  if (region == 0) {                  // q: softmax over e (in-wave), *0.125
#pragma unroll
    for (int m = 0; m < 2; ++m) {
#pragma unroll
      for (int i = 0; i < 4; ++i) {
        float v[4];
#pragma unroll
        for (int n = 0; n < 4; ++n) v[n] = acc[m][n][i] + bv[n];
        float mx = fmaxf(fmaxf(v[0], v[1]), fmaxf(v[2], v[3]));
#pragma unroll
        for (int off = 1; off <= 8; off <<= 1) mx = fmaxf(mx, __shfl_xor(mx, off));
        float s = 0.f;
#pragma unroll
        for (int n = 0; n < 4; ++n) { v[n] = __expf(v[n] - mx); s += v[n]; }
#pragma unroll
        for (int off = 1; off <= 8; off <<= 1) s += __shfl_xor(s, off);
        float inv = 0.125f / s;
        int tok = r0 + 16 * m + 4 * g2 + i;
        unsigned short* qrow = qh + ((size_t)h * NTOK + tok) * 64;
#pragma unroll
        for (int n = 0; n < 4; ++n) qrow[16 * n + ocol] = f2bf(v[n] * inv);
      }
    }
  } else if (region == 1) {           // v: write transposed vt[h][c][e][tok]
    unsigned short* vb = vt + (size_t)(h * NCH + cch) * 4096;
#pragma unroll
    for (int m = 0; m < 2; ++m) {
      int tl = lbase + 16 * m + 4 * g2;
#pragma unroll
      for (int n = 0; n < 4; ++n) {
        int e = 16 * n + ocol;
        ushort4 p = { f2bf(acc[m][n][0] + bv[n]), f2bf(acc[m][n][1] + bv[n]),
                      f2bf(acc[m][n][2] + bv[n]), f2bf(acc[m][n][3] + bv[n]) };
        *(ushort4*)&vb[(size_t)e * 64 + tl] = p;
      }
    }
  } else {                            // k: exp, write kh + kt, accumulate z partials
    unsigned short* kb = kt + (size_t)(h * NCH + cch) * 4096;
    float pz[4] = {0.f, 0.f, 0.f, 0.f};
#pragma unroll
    for (int m = 0; m < 2; ++m) {
      int tl = lbase + 16 * m + 4 * g2;
#pragma unroll
      for (int n = 0; n < 4; ++n) {
        int e = 16 * n + ocol;
        float kv[4];
#pragma unroll
        for (int i = 0; i < 4; ++i) kv[i] = __expf(acc[m][n][i] + bv[n]);
        pz[n] += kv[0] + kv[1] + kv[2] + kv[3];
        ushort4 p = { f2bf(kv[0]), f2bf(kv[1]), f2bf(kv[2]), f2bf(kv[3]) };
        *(ushort4*)&kb[(size_t)e * 64 + tl] = p;
#pragma unroll
        for (int i = 0; i < 4; ++i)
          kh[((size_t)h * NTOK + r0 + 16 * m + 4 * g2 + i) * 64 + e] = p[i];
      }
    }
    // reduce over the 4 lane-groups (g2), then 2 atomics/elem across the 2 waves of this chunk
#pragma unroll
    for (int n = 0; n < 4; ++n) {
      pz[n] += __shfl_xor(pz[n], 16);
      pz[n] += __shfl_xor(pz[n], 32);
    }
    if (g2 == 0) {
      float* zrow = zc + (size_t)(h * NCH + cch) * 64;
#pragma unroll
      for (int n = 0; n < 4; ++n) atomicAdd(&zrow[16 * n + ocol], pz[n]);
    }
  }
}

// ---- fused chunk-sums + exclusive scan: running prefix lives in the MFMA accumulator ----
// 64 blocks = (h, e'-quarter q); 4 waves = d-quarters. Operands straight from global.
// Sp[h][c][e'][d] (bf16) = sum over chunks cc<c of K_cc V_cc^T (stored transposed, same
// layout the attn kernel already consumes).
__global__ __launch_bounds__(256) void k_sumscan(const unsigned short* __restrict__ kt,
                                                 const unsigned short* __restrict__ vt,
                                                 unsigned short* __restrict__ Sp) {
  const int h = blockIdx.x >> 2, q = blockIdx.x & 3;
  const int t = threadIdx.x, lane = t & 63, w = t >> 6;
  const int fr = lane & 15, g = lane >> 4, fko = g * 8;
  const unsigned short* kbase = kt + (size_t)h * NCH * 4096 + (16 * w + fr) * 64 + fko;
  const unsigned short* vbase = vt + (size_t)h * NCH * 4096 + (q * 16 + fr) * 64 + fko;
  unsigned short* spb = Sp + (size_t)h * NCH * 4096 + (q * 16 + fr) * 64 + 16 * w + 4 * g;
  f32x4 run = {};
#pragma unroll 2
  for (int c = 0; c < NCH; ++c) {
    bf16x8 ka0 = *(const bf16x8*)(kbase + (size_t)c * 4096);
    bf16x8 ka1 = *(const bf16x8*)(kbase + (size_t)c * 4096 + 32);
    bf16x8 vf0 = *(const bf16x8*)(vbase + (size_t)c * 4096);
    bf16x8 vf1 = *(const bf16x8*)(vbase + (size_t)c * 4096 + 32);
    ushort4 o = { f2bf(run[0]), f2bf(run[1]), f2bf(run[2]), f2bf(run[3]) };
    *(ushort4*)(spb + (size_t)c * 4096) = o;       // exclusive: write BEFORE accumulating c
    run = __builtin_amdgcn_mfma_f32_16x16x32_bf16(ka0, vf0, run, 0, 0, 0);
    run = __builtin_amdgcn_mfma_f32_16x16x32_bf16(ka1, vf1, run, 0, 0, 0);
  }
}

// ---- attention: O = M(QK^T) V + Q S_prev, denom fused; z-prefix computed inline ----
__global__ __launch_bounds__(256) void k_attn(const unsigned short* __restrict__ qh,
                                              const unsigned short* __restrict__ kh,
                                              const unsigned short* __restrict__ vt,
                                              const unsigned short* __restrict__ Sp,
                                              const float* __restrict__ zc,
                                              float* __restrict__ out) {
  int h = blockIdx.x >> 5, c = blockIdx.x & 31;
  __shared__ __align__(16) unsigned short Qs[64][72], Ks[64][72], Vts[64][72], Sts[64][72], Ams[64][72];
  __shared__ float zs[64], denom[64];
  int t = threadIdx.x, lane = t & 63, w = t >> 6;
  int fr = lane & 15, g = lane >> 4, fko = g * 8;
  const unsigned short* qg = qh + ((size_t)h * NTOK + c * 64) * 64;
  const unsigned short* kg = kh + ((size_t)h * NTOK + c * 64) * 64;
  const unsigned short* vg = vt + (size_t)(h * NCH + c) * 4096;
  const unsigned short* sg = Sp + (size_t)(h * NCH + c) * 4096;
  for (int s = t; s < 512; s += 256) {
    int r = s >> 3, c8 = (s & 7) * 8;
    *(ushort8v*)&Qs[r][c8]  = *(const ushort8v*)&qg[r * 64 + c8];
    *(ushort8v*)&Ks[r][c8]  = *(const ushort8v*)&kg[r * 64 + c8];
    *(ushort8v*)&Vts[r][c8] = *(const ushort8v*)&vg[r * 64 + c8];
    *(ushort8v*)&Sts[r][c8] = *(const ushort8v*)&sg[r * 64 + c8];
  }
  if (t < 64) {
    const float* zb = zc + (size_t)h * NCH * 64 + t;
    float z0 = 0.f, z1 = 0.f, z2 = 0.f, z3 = 0.f;
    int cc = 0;
    for (; cc + 4 <= c; cc += 4) {
      z0 += zb[(size_t)cc * 64];
      z1 += zb[(size_t)(cc + 1) * 64];
      z2 += zb[(size_t)(cc + 2) * 64];
      z3 += zb[(size_t)(cc + 3) * 64];
    }
    for (; cc < c; ++cc) z0 += zb[(size_t)cc * 64];
    zs[t] = (z0 + z1) + (z2 + z3);
  }
  __syncthreads();

  // step 1: A = Q K^T
  bf16x8 qa[2];
#pragma unroll
  for (int ks = 0; ks < 2; ++ks) qa[ks] = *(const bf16x8*)&Qs[16 * w + fr][32 * ks + fko];
  f32x4 a1[4] = {};
#pragma unroll
  for (int mb = 0; mb < 4; ++mb)
#pragma unroll
    for (int ks = 0; ks < 2; ++ks) {
      bf16x8 kf = *(const bf16x8*)&Ks[16 * mb + fr][32 * ks + fko];
      a1[mb] = __builtin_amdgcn_mfma_f32_16x16x32_bf16(qa[ks], kf, a1[mb], 0, 0, 0);
    }
#pragma unroll
  for (int i = 0; i < 4; ++i) {
    int n = 16 * w + 4 * g + i;
    float rs = 0.f;
#pragma unroll
    for (int j = 0; j < 4; ++j) rs += bf2f(Qs[n][fr * 4 + j]) * zs[fr * 4 + j];
#pragma unroll
    for (int mb = 0; mb < 4; ++mb) {
      int m = 16 * mb + fr;
      float v = (m <= n) ? a1[mb][i] : 0.f;
      a1[mb][i] = v;
      rs += v;
      Ams[n][16 * mb + fr] = f2bf(v);
    }
#pragma unroll
    for (int off = 1; off <= 8; off <<= 1) rs += __shfl_xor(rs, off);
    if (fr == 0) denom[n] = rs + 1.25e-7f;   // eps * sum(q) = 1e-6 * 0.125
  }
  __syncthreads();

  // step 2: O^T[e'][n] = Vt·A + St·Q
  bf16x8 xa[4];
#pragma unroll
  for (int ks = 0; ks < 2; ++ks) {
    xa[ks]     = *(const bf16x8*)&Vts[16 * w + fr][32 * ks + fko];
    xa[2 + ks] = *(const bf16x8*)&Sts[16 * w + fr][32 * ks + fko];
  }
  f32x4 o4[4] = {};
#pragma unroll
  for (int nb = 0; nb < 4; ++nb)
#pragma unroll
    for (int ks = 0; ks < 2; ++ks) {
      bf16x8 afr = *(const bf16x8*)&Ams[16 * nb + fr][32 * ks + fko];
      o4[nb] = __builtin_amdgcn_mfma_f32_16x16x32_bf16(xa[ks], afr, o4[nb], 0, 0, 0);
      bf16x8 qfr = *(const bf16x8*)&Qs[16 * nb + fr][32 * ks + fko];
      o4[nb] = __builtin_amdgcn_mfma_f32_16x16x32_bf16(xa[2 + ks], qfr, o4[nb], 0, 0, 0);
    }
#pragma unroll
  for (int nb = 0; nb < 4; ++nb) {
    int n = 16 * nb + fr;
    float dv = denom[n];
    float4 res = { o4[nb][0] / dv, o4[nb][1] / dv, o4[nb][2] / dv, o4[nb][3] / dv };
    *(float4*)&out[(size_t)(c * 64 + n) * 1024 + h * 64 + 16 * w + 4 * g] = res;
  }
}

extern "C" void kernel_launch(void* const* d_in, const int* in_sizes, int n_in,
                              void* d_out, int out_size, void* d_ws, size_t ws_size,
                              hipStream_t stream) {
  (void)in_sizes; (void)n_in; (void)out_size; (void)ws_size;
  const float* x = (const float*)d_in[0];
  const float* W = (const float*)d_in[1];
  const float* b = (const float*)d_in[2];
  char* ws = (char*)d_ws;

  const size_t MB = 1024 * 1024;
  unsigned short* xb = (unsigned short*)(ws + 0);        // 4 MB
  unsigned short* Wt = (unsigned short*)(ws + 4 * MB);   // 6 MB
  unsigned short* qh = (unsigned short*)(ws + 10 * MB);  // 4 MB
  unsigned short* kh = (unsigned short*)(ws + 14 * MB);  // 4 MB
  unsigned short* kt = (unsigned short*)(ws + 18 * MB);  // 4 MB
  unsigned short* vt = (unsigned short*)(ws + 22 * MB);  // 4 MB
  unsigned short* Sp = (unsigned short*)(ws + 26 * MB);  // 4 MB (bf16 exclusive prefix)
  float*          zc = (float*)(ws + 30 * MB);           // 128 KB (per-chunk z, atomically built)

  hipMemsetAsync(zc, 0, (size_t)16 * 32 * 64 * sizeof(float), stream);
  k_prep_inputs<<<dim3(5120), dim3(256), 0, stream>>>(x, xb, W, Wt);
  k_gemm_fused<<<dim3(16, 16), dim3(768), 0, stream>>>(xb, Wt, b, qh, kh, kt, vt, zc);
  k_sumscan<<<dim3(64), dim3(256), 0, stream>>>(kt, vt, Sp);
  k_attn<<<dim3(512), dim3(256), 0, stream>>>(qh, kh, vt, Sp, zc, (float*)d_out);
}

// Round 14
// 47.285 us; speedup vs baseline: 1.3425x; 1.3425x over previous
//
#include <hip/hip_runtime.h>
#include <stdint.h>

// B=1, N=2048, D=1024, h=16, e=64; chunks of 64 tokens -> 32 chunks/head
#define NTOK 2048
#define NCH 32

typedef __attribute__((ext_vector_type(8))) short bf16x8;
typedef __attribute__((ext_vector_type(8))) unsigned short ushort8v;
typedef __attribute__((ext_vector_type(4))) float f32x4;

__device__ __forceinline__ unsigned short f2bf(float f) {
  unsigned u = __float_as_uint(f);
  u += 0x7fffu + ((u >> 16) & 1u);   // RNE
  return (unsigned short)(u >> 16);
}
__device__ __forceinline__ float bf2f(unsigned short s) {
  return __uint_as_float(((unsigned)s) << 16);
}

// ---- fused input prep: x -> bf16 (blocks 0..2047), W -> Wt bf16 transposed (blocks 2048..5119) ----
__global__ __launch_bounds__(256) void k_prep_inputs(const float* __restrict__ x,
                                                     unsigned short* __restrict__ xb,
                                                     const float* __restrict__ W,
                                                     unsigned short* __restrict__ Wt) {
  int bid = blockIdx.x;
  if (bid < 2048) {
    int i = (bid * 256 + threadIdx.x) * 4;
    float4 v = *(const float4*)(x + i);
    ushort4 o = { f2bf(v.x), f2bf(v.y), f2bf(v.z), f2bf(v.w) };
    *(ushort4*)(xb + i) = o;
  } else {
    __shared__ float tile[32][33];
    int id = bid - 2048;            // 3072 blocks: bx in [0,96), by in [0,32)
    int bx = id % 96, by = id / 96;
    int tx = threadIdx.x & 31, ty = threadIdx.x >> 5;
    int c0 = bx * 32;
    int r0 = by * 32;
#pragma unroll
    for (int j = 0; j < 32; j += 8)
      tile[ty + j][tx] = W[(size_t)(r0 + ty + j) * 3072 + c0 + tx];
    __syncthreads();
#pragma unroll
    for (int j = 0; j < 32; j += 8)
      Wt[(size_t)(c0 + ty + j) * 1024 + r0 + tx] = f2bf(tile[tx][ty + j]);
  }
}

// ---- GEMM 2048x3072, 128x192 tile, 768 thr (12 waves of 32x64), BK=64 ----
// 3-buffer, SINGLE barrier per K-tile (T3 recipe): STG issued right after the
// barrier (before ds_reads), targeting the buffer consumed last iteration.
// Counted vmcnt (A-waves 4, B-waves 3); drain only at the final tile.
// grid (16,16) = 256 blocks = 1 block/CU; LDS 120 KB.
__global__ __launch_bounds__(768, 1) void k_gemm_fused(const unsigned short* __restrict__ xb,
                                                       const unsigned short* __restrict__ wt,
                                                       const float* __restrict__ bias,
                                                       unsigned short* __restrict__ qh,
                                                       unsigned short* __restrict__ kh,
                                                       unsigned short* __restrict__ kt,
                                                       unsigned short* __restrict__ vt) {
  __shared__ __align__(16) unsigned short As[3][128][64];    // 3 x 16 KB
  __shared__ __align__(16) unsigned short Bs[3][192][64];    // 3 x 24 KB
  const int t = threadIdx.x;           // 0..767
  const int lane = t & 63;
  const int wave = t >> 6;             // 0..11
  const int wr = wave / 3;             // 0..3 (32-row block)
  const int wc = wave % 3;             // 0..2 (64-col block)
  const int rowBase = blockIdx.y * 128;
  const int colBase = blockIdx.x * 192;
  const int fr = lane & 15;
  const int khalf = lane >> 4;         // 0..3

  // staging: A = 1024 chunks over threads 0..255 (4 each); B = 1536 over 256..767 (3 each)
  const bool isA = t < 256;            // wave-uniform (boundary at wave 4)
  const int nL = isA ? 4 : 3;
  const int bstr = isA ? 16384 : 24576;
  const unsigned short* gsrc[4];
  char* ldst[4];
#pragma unroll
  for (int j = 0; j < 4; ++j) {
    int idx = isA ? (t + j * 256) : (t - 256 + j * 512);
    if (j >= nL) idx = 0;              // dummy, never issued
    int row = idx >> 3;
    int ssl = (idx & 7) ^ (row & 7);   // XOR swizzle (inverse on source)
    gsrc[j] = (isA ? xb + (size_t)(rowBase + row) * 1024
                   : wt + (size_t)(colBase + row) * 1024) + ssl * 8;
    ldst[j] = (isA ? (char*)As : (char*)Bs) + idx * 16;
  }

#define STG(buf, kt0) do {                                                                \
    _Pragma("unroll")                                                                     \
    for (int j_ = 0; j_ < 4; ++j_)                                                        \
      if (j_ < nL)                                                                        \
        __builtin_amdgcn_global_load_lds(                                                 \
            (const __attribute__((address_space(1))) void*)(gsrc[j_] + (kt0) * 64),       \
            (__attribute__((address_space(3))) void*)(ldst[j_] + (buf) * bstr), 16, 0, 0);\
  } while (0)

#define VMW_STEADY() do {                                                                 \
    if (isA) asm volatile("s_waitcnt vmcnt(4)" ::: "memory");                             \
    else     asm volatile("s_waitcnt vmcnt(3)" ::: "memory");                             \
  } while (0)
#define VMCNT0() asm volatile("s_waitcnt vmcnt(0)" ::: "memory")
#define LGKM0()  asm volatile("s_waitcnt lgkmcnt(0)" ::: "memory")
#define BAR()    __builtin_amdgcn_s_barrier()

  f32x4 acc[2][4] = {};
  const int fs0 = khalf ^ (fr & 7);   // swizzled slot for ks=0; ks=1 is fs0^4

#define LOAD_FRAGS(cur, af, bff) do {                                                     \
    _Pragma("unroll")                                                                     \
    for (int m = 0; m < 2; ++m) {                                                         \
      const unsigned short* r = &As[cur][wr * 32 + m * 16 + fr][0];                       \
      af[m][0] = *(const bf16x8*)(r + fs0 * 8);                                           \
      af[m][1] = *(const bf16x8*)(r + (fs0 ^ 4) * 8);                                     \
    }                                                                                     \
    _Pragma("unroll")                                                                     \
    for (int n = 0; n < 4; ++n) {                                                         \
      const unsigned short* r = &Bs[cur][wc * 64 + n * 16 + fr][0];                       \
      bff[n][0] = *(const bf16x8*)(r + fs0 * 8);                                          \
      bff[n][1] = *(const bf16x8*)(r + (fs0 ^ 4) * 8);                                    \
    }                                                                                     \
  } while (0)

#define DO_MFMA(af, bff) do {                                                             \
    _Pragma("unroll")                                                                     \
    for (int m = 0; m < 2; ++m)                                                           \
      _Pragma("unroll")                                                                   \
      for (int n = 0; n < 4; ++n) {                                                       \
        acc[m][n] = __builtin_amdgcn_mfma_f32_16x16x32_bf16(af[m][0], bff[n][0], acc[m][n], 0, 0, 0); \
        acc[m][n] = __builtin_amdgcn_mfma_f32_16x16x32_bf16(af[m][1], bff[n][1], acc[m][n], 0, 0, 0); \
      }                                                                                   \
  } while (0)

  STG(0, 0);
  STG(1, 1);
#pragma unroll 1
  for (int ktile = 0; ktile < 16; ++ktile) {
    const int cur = ktile % 3;
    if (ktile < 15) { VMW_STEADY(); }   // tile `ktile` landed; tile ktile+1 in flight
    else            { VMCNT0(); }
    BAR();                              // all waves consumed buf[(ktile-1)%3] last iter
    __builtin_amdgcn_sched_barrier(0);
    if (ktile < 14) STG((ktile + 2) % 3, ktile + 2);   // overwrites the consumed buffer
    bf16x8 af[2][2], bff[4][2];
    LOAD_FRAGS(cur, af, bff);
    LGKM0();                            // my ds_reads complete (values in regs)
    __builtin_amdgcn_sched_barrier(0);
    __builtin_amdgcn_s_setprio(1);
    DO_MFMA(af, bff);
    __builtin_amdgcn_s_setprio(0);
  }
#undef STG
#undef LOAD_FRAGS
#undef DO_MFMA

  // ---- fused epilogue (R4/R8-verified: per wave 32 rows x one 64-col head span) ----
  const int g2 = khalf;               // C row group: row = 4*g2+i
  const int ocol = lane & 15;         // C col within 16-block
  const int col0 = colBase + wc * 64; // this wave's 64-col span = one head-region
  const int region = col0 >> 10;      // 0=q 1=v 2=k
  const int h = (col0 & 1023) >> 6;
  const int r0 = rowBase + wr * 32;   // global token base of this wave
  const int cch = r0 >> 6;            // chunk index
  const int lbase = (wr & 1) * 32;    // chunk-local row base
  float bv[4];
#pragma unroll
  for (int n = 0; n < 4; ++n) bv[n] = bias[col0 + 16 * n + ocol];

  if (region == 0) {                  // q: softmax over e (in-wave), *0.125
#pragma unroll
    for (int m = 0; m < 2; ++m) {
#pragma unroll
      for (int i = 0; i < 4; ++i) {
        float v[4];
#pragma unroll
        for (int n = 0; n < 4; ++n) v[n] = acc[m][n][i] + bv[n];
        float mx = fmaxf(fmaxf(v[0], v[1]), fmaxf(v[2], v[3]));
#pragma unroll
        for (int off = 1; off <= 8; off <<= 1) mx = fmaxf(mx, __shfl_xor(mx, off));
        float s = 0.f;
#pragma unroll
        for (int n = 0; n < 4; ++n) { v[n] = __expf(v[n] - mx); s += v[n]; }
#pragma unroll
        for (int off = 1; off <= 8; off <<= 1) s += __shfl_xor(s, off);
        float inv = 0.125f / s;
        int tok = r0 + 16 * m + 4 * g2 + i;
        unsigned short* qrow = qh + ((size_t)h * NTOK + tok) * 64;
#pragma unroll
        for (int n = 0; n < 4; ++n) qrow[16 * n + ocol] = f2bf(v[n] * inv);
      }
    }
  } else if (region == 1) {           // v: write transposed vt[h][c][e][tok]
    unsigned short* vb = vt + (size_t)(h * NCH + cch) * 4096;
#pragma unroll
    for (int m = 0; m < 2; ++m) {
      int tl = lbase + 16 * m + 4 * g2;
#pragma unroll
      for (int n = 0; n < 4; ++n) {
        int e = 16 * n + ocol;
        ushort4 p = { f2bf(acc[m][n][0] + bv[n]), f2bf(acc[m][n][1] + bv[n]),
                      f2bf(acc[m][n][2] + bv[n]), f2bf(acc[m][n][3] + bv[n]) };
        *(ushort4*)&vb[(size_t)e * 64 + tl] = p;
      }
    }
  } else {                            // k: exp, write kh row-major + kt transposed
    unsigned short* kb = kt + (size_t)(h * NCH + cch) * 4096;
#pragma unroll
    for (int m = 0; m < 2; ++m) {
      int tl = lbase + 16 * m + 4 * g2;
#pragma unroll
      for (int n = 0; n < 4; ++n) {
        int e = 16 * n + ocol;
        float kv[4];
#pragma unroll
        for (int i = 0; i < 4; ++i) kv[i] = __expf(acc[m][n][i] + bv[n]);
        ushort4 p = { f2bf(kv[0]), f2bf(kv[1]), f2bf(kv[2]), f2bf(kv[3]) };
        *(ushort4*)&kb[(size_t)e * 64 + tl] = p;
#pragma unroll
        for (int i = 0; i < 4; ++i)
          kh[((size_t)h * NTOK + r0 + 16 * m + 4 * g2 + i) * 64 + e] = p[i];
      }
    }
  }
}

// ---- per-(h,c) chunk sums via MFMA: stored as ScT[e'][d] f32; z[d] f32 ----
__global__ __launch_bounds__(256) void k_chunk_sums(const unsigned short* __restrict__ kt,
                                                    const unsigned short* __restrict__ vt,
                                                    float* __restrict__ Sc,
                                                    float* __restrict__ zc) {
  int h = blockIdx.x >> 5, c = blockIdx.x & 31;
  __shared__ __align__(16) unsigned short Kt[64][72], Vt[64][72];
  int t = threadIdx.x, lane = t & 63, w = t >> 6;
  int fr = lane & 15, g = lane >> 4, fko = g * 8;
  const unsigned short* kg = kt + (size_t)(h * NCH + c) * 4096;
  const unsigned short* vg = vt + (size_t)(h * NCH + c) * 4096;
  for (int s = t; s < 512; s += 256) {
    int r = s >> 3, c8 = (s & 7) * 8;
    *(ushort8v*)&Kt[r][c8] = *(const ushort8v*)&kg[r * 64 + c8];
    *(ushort8v*)&Vt[r][c8] = *(const ushort8v*)&vg[r * 64 + c8];
  }
  __syncthreads();
  bf16x8 ka[2];
#pragma unroll
  for (int ks = 0; ks < 2; ++ks) ka[ks] = *(const bf16x8*)&Kt[16 * w + fr][32 * ks + fko];
  f32x4 s4[4] = {};
#pragma unroll
  for (int nb = 0; nb < 4; ++nb)
#pragma unroll
    for (int ks = 0; ks < 2; ++ks) {
      bf16x8 vf = *(const bf16x8*)&Vt[16 * nb + fr][32 * ks + fko];
      s4[nb] = __builtin_amdgcn_mfma_f32_16x16x32_bf16(ka[ks], vf, s4[nb], 0, 0, 0);
    }
  float* so = Sc + (size_t)(h * NCH + c) * 4096;   // [e'][d]
#pragma unroll
  for (int nb = 0; nb < 4; ++nb) {
    float4 o = { s4[nb][0], s4[nb][1], s4[nb][2], s4[nb][3] };
    *(float4*)&so[(size_t)(16 * nb + fr) * 64 + 16 * w + 4 * g] = o;
  }
  if (w == 0) {
    float z = 0.f;
#pragma unroll
    for (int j = 0; j < 8; ++j) {
      bf16x8 kv = *(const bf16x8*)&Kt[lane][j * 8];
#pragma unroll
      for (int e = 0; e < 8; ++e) z += bf2f((unsigned short)kv[e]);
    }
    zc[(size_t)(h * NCH + c) * 64 + lane] = z;
  }
}

// ---- exclusive prefix over chunks, element-parallel; S out as bf16 ----
__global__ __launch_bounds__(256) void k_scan(const float* __restrict__ Sc,
                                              unsigned short* __restrict__ Sp,
                                              const float* __restrict__ zc,
                                              float* __restrict__ zp) {
  int b = blockIdx.x;
  if (b < 256) {
    int tg = b * 256 + threadIdx.x;
    int h = tg >> 12, e = tg & 4095;
    float run = 0.f;
    for (int c = 0; c < NCH; ++c) {
      size_t idx = (size_t)(h * NCH + c) * 4096 + e;
      float v = Sc[idx];
      Sp[idx] = f2bf(run);
      run += v;
    }
  } else {
#pragma unroll
    for (int j = 0; j < 4; ++j) {
      int s = threadIdx.x + j * 256;
      int h = s >> 6, d = s & 63;
      float run = 0.f;
      for (int c = 0; c < NCH; ++c) {
        size_t idx = (size_t)(h * NCH + c) * 64 + d;
        zp[idx] = run;
        run += zc[idx];
      }
    }
  }
}

// ---- attention: O = M(QK^T) V + Q S_prev, denom fused; all MFMA ----
__global__ __launch_bounds__(256) void k_attn(const unsigned short* __restrict__ qh,
                                              const unsigned short* __restrict__ kh,
                                              const unsigned short* __restrict__ vt,
                                              const unsigned short* __restrict__ Sp,
                                              const float* __restrict__ zp,
                                              float* __restrict__ out) {
  int h = blockIdx.x >> 5, c = blockIdx.x & 31;
  __shared__ __align__(16) unsigned short Qs[64][72], Ks[64][72], Vts[64][72], Sts[64][72], Ams[64][72];
  __shared__ float zs[64], denom[64];
  int t = threadIdx.x, lane = t & 63, w = t >> 6;
  int fr = lane & 15, g = lane >> 4, fko = g * 8;
  const unsigned short* qg = qh + ((size_t)h * NTOK + c * 64) * 64;
  const unsigned short* kg = kh + ((size_t)h * NTOK + c * 64) * 64;
  const unsigned short* vg = vt + (size_t)(h * NCH + c) * 4096;
  const unsigned short* sg = Sp + (size_t)(h * NCH + c) * 4096;
  for (int s = t; s < 512; s += 256) {
    int r = s >> 3, c8 = (s & 7) * 8;
    *(ushort8v*)&Qs[r][c8]  = *(const ushort8v*)&qg[r * 64 + c8];
    *(ushort8v*)&Ks[r][c8]  = *(const ushort8v*)&kg[r * 64 + c8];
    *(ushort8v*)&Vts[r][c8] = *(const ushort8v*)&vg[r * 64 + c8];
    *(ushort8v*)&Sts[r][c8] = *(const ushort8v*)&sg[r * 64 + c8];
  }
  if (t < 64) zs[t] = zp[(size_t)(h * NCH + c) * 64 + t];
  __syncthreads();

  // step 1: A = Q K^T
  bf16x8 qa[2];
#pragma unroll
  for (int ks = 0; ks < 2; ++ks) qa[ks] = *(const bf16x8*)&Qs[16 * w + fr][32 * ks + fko];
  f32x4 a1[4] = {};
#pragma unroll
  for (int mb = 0; mb < 4; ++mb)
#pragma unroll
    for (int ks = 0; ks < 2; ++ks) {
      bf16x8 kf = *(const bf16x8*)&Ks[16 * mb + fr][32 * ks + fko];
      a1[mb] = __builtin_amdgcn_mfma_f32_16x16x32_bf16(qa[ks], kf, a1[mb], 0, 0, 0);
    }
#pragma unroll
  for (int i = 0; i < 4; ++i) {
    int n = 16 * w + 4 * g + i;
    float rs = 0.f;
#pragma unroll
    for (int j = 0; j < 4; ++j) rs += bf2f(Qs[n][fr * 4 + j]) * zs[fr * 4 + j];
#pragma unroll
    for (int mb = 0; mb < 4; ++mb) {
      int m = 16 * mb + fr;
      float v = (m <= n) ? a1[mb][i] : 0.f;
      a1[mb][i] = v;
      rs += v;
      Ams[n][16 * mb + fr] = f2bf(v);
    }
#pragma unroll
    for (int off = 1; off <= 8; off <<= 1) rs += __shfl_xor(rs, off);
    if (fr == 0) denom[n] = rs + 1.25e-7f;   // eps * sum(q) = 1e-6 * 0.125
  }
  __syncthreads();

  // step 2: O^T[e'][n] = Vt·A + St·Q
  bf16x8 xa[4];
#pragma unroll
  for (int ks = 0; ks < 2; ++ks) {
    xa[ks]     = *(const bf16x8*)&Vts[16 * w + fr][32 * ks + fko];
    xa[2 + ks] = *(const bf16x8*)&Sts[16 * w + fr][32 * ks + fko];
  }
  f32x4 o4[4] = {};
#pragma unroll
  for (int nb = 0; nb < 4; ++nb)
#pragma unroll
    for (int ks = 0; ks < 2; ++ks) {
      bf16x8 afr = *(const bf16x8*)&Ams[16 * nb + fr][32 * ks + fko];
      o4[nb] = __builtin_amdgcn_mfma_f32_16x16x32_bf16(xa[ks], afr, o4[nb], 0, 0, 0);
      bf16x8 qfr = *(const bf16x8*)&Qs[16 * nb + fr][32 * ks + fko];
      o4[nb] = __builtin_amdgcn_mfma_f32_16x16x32_bf16(xa[2 + ks], qfr, o4[nb], 0, 0, 0);
    }
#pragma unroll
  for (int nb = 0; nb < 4; ++nb) {
    int n = 16 * nb + fr;
    float dv = denom[n];
    float4 res = { o4[nb][0] / dv, o4[nb][1] / dv, o4[nb][2] / dv, o4[nb][3] / dv };
    *(float4*)&out[(size_t)(c * 64 + n) * 1024 + h * 64 + 16 * w + 4 * g] = res;
  }
}

extern "C" void kernel_launch(void* const* d_in, const int* in_sizes, int n_in,
                              void* d_out, int out_size, void* d_ws, size_t ws_size,
                              hipStream_t stream) {
  (void)in_sizes; (void)n_in; (void)out_size; (void)ws_size;
  const float* x = (const float*)d_in[0];
  const float* W = (const float*)d_in[1];
  const float* b = (const float*)d_in[2];
  char* ws = (char*)d_ws;

  const size_t MB = 1024 * 1024;
  unsigned short* xb = (unsigned short*)(ws + 0);        // 4 MB
  unsigned short* Wt = (unsigned short*)(ws + 4 * MB);   // 6 MB
  unsigned short* qh = (unsigned short*)(ws + 10 * MB);  // 4 MB
  unsigned short* kh = (unsigned short*)(ws + 14 * MB);  // 4 MB
  unsigned short* kt = (unsigned short*)(ws + 18 * MB);  // 4 MB
  unsigned short* vt = (unsigned short*)(ws + 22 * MB);  // 4 MB
  float*          Sc = (float*)(ws + 26 * MB);           // 8 MB (f32 chunk sums)
  unsigned short* Sp = (unsigned short*)(ws + 34 * MB);  // 4 MB (bf16 exclusive prefix)
  float*          zc = (float*)(ws + 38 * MB);           // 128 KB
  float*          zp = (float*)(ws + 38 * MB + 131072);  // 128 KB

  k_prep_inputs<<<dim3(5120), dim3(256), 0, stream>>>(x, xb, W, Wt);
  k_gemm_fused<<<dim3(16, 16), dim3(768), 0, stream>>>(xb, Wt, b, qh, kh, kt, vt);
  k_chunk_sums<<<dim3(512), dim3(256), 0, stream>>>(kt, vt, Sc, zc);
  k_scan<<<dim3(257), dim3(256), 0, stream>>>(Sc, Sp, zc, zp);
  k_attn<<<dim3(512), dim3(256), 0, stream>>>(qh, kh, vt, Sp, zp, (float*)d_out);
}

// Round 15
// 46.328 us; speedup vs baseline: 1.3702x; 1.0206x over previous
//
#include <hip/hip_runtime.h>
#include <stdint.h>

// B=1, N=2048, D=1024, h=16, e=64; chunks of 64 tokens -> 32 chunks/head
#define NTOK 2048
#define NCH 32

typedef __attribute__((ext_vector_type(8))) short bf16x8;
typedef __attribute__((ext_vector_type(8))) unsigned short ushort8v;
typedef __attribute__((ext_vector_type(4))) float f32x4;

__device__ __forceinline__ unsigned short f2bf(float f) {
  unsigned u = __float_as_uint(f);
  u += 0x7fffu + ((u >> 16) & 1u);   // RNE
  return (unsigned short)(u >> 16);
}
__device__ __forceinline__ float bf2f(unsigned short s) {
  return __uint_as_float(((unsigned)s) << 16);
}

// ---- fused input prep: x -> bf16 (blocks 0..2047), W -> Wt bf16 transposed (blocks 2048..5119) ----
__global__ __launch_bounds__(256) void k_prep_inputs(const float* __restrict__ x,
                                                     unsigned short* __restrict__ xb,
                                                     const float* __restrict__ W,
                                                     unsigned short* __restrict__ Wt) {
  int bid = blockIdx.x;
  if (bid < 2048) {
    int i = (bid * 256 + threadIdx.x) * 4;
    float4 v = *(const float4*)(x + i);
    ushort4 o = { f2bf(v.x), f2bf(v.y), f2bf(v.z), f2bf(v.w) };
    *(ushort4*)(xb + i) = o;
  } else {
    __shared__ float tile[32][33];
    int id = bid - 2048;            // 3072 blocks: bx in [0,96), by in [0,32)
    int bx = id % 96, by = id / 96;
    int tx = threadIdx.x & 31, ty = threadIdx.x >> 5;
    int c0 = bx * 32;
    int r0 = by * 32;
#pragma unroll
    for (int j = 0; j < 32; j += 8)
      tile[ty + j][tx] = W[(size_t)(r0 + ty + j) * 3072 + c0 + tx];
    __syncthreads();
#pragma unroll
    for (int j = 0; j < 32; j += 8)
      Wt[(size_t)(c0 + ty + j) * 1024 + r0 + tx] = f2bf(tile[tx][ty + j]);
  }
}

// ---- GEMM 2048x3072, 128x192 tile, 768 thr (12 waves of 32x64), BK=64 ----
// R14-verified: 3-buffer, SINGLE barrier per K-tile, counted vmcnt (A 4 / B 3).
// R15 micro: ds_reads issued BEFORE the STG batch (lgkm stall starts earlier;
// prefetch still 1.5 tiles deep). grid (16,16) = 1 block/CU; LDS 120 KB.
__global__ __launch_bounds__(768, 1) void k_gemm_fused(const unsigned short* __restrict__ xb,
                                                       const unsigned short* __restrict__ wt,
                                                       const float* __restrict__ bias,
                                                       unsigned short* __restrict__ qh,
                                                       unsigned short* __restrict__ kh,
                                                       unsigned short* __restrict__ kt,
                                                       unsigned short* __restrict__ vt) {
  __shared__ __align__(16) unsigned short As[3][128][64];    // 3 x 16 KB
  __shared__ __align__(16) unsigned short Bs[3][192][64];    // 3 x 24 KB
  const int t = threadIdx.x;           // 0..767
  const int lane = t & 63;
  const int wave = t >> 6;             // 0..11
  const int wr = wave / 3;             // 0..3 (32-row block)
  const int wc = wave % 3;             // 0..2 (64-col block)
  const int rowBase = blockIdx.y * 128;
  const int colBase = blockIdx.x * 192;
  const int fr = lane & 15;
  const int khalf = lane >> 4;         // 0..3

  // staging: A = 1024 chunks over threads 0..255 (4 each); B = 1536 over 256..767 (3 each)
  const bool isA = t < 256;            // wave-uniform (boundary at wave 4)
  const int nL = isA ? 4 : 3;
  const int bstr = isA ? 16384 : 24576;
  const unsigned short* gsrc[4];
  char* ldst[4];
#pragma unroll
  for (int j = 0; j < 4; ++j) {
    int idx = isA ? (t + j * 256) : (t - 256 + j * 512);
    if (j >= nL) idx = 0;              // dummy, never issued
    int row = idx >> 3;
    int ssl = (idx & 7) ^ (row & 7);   // XOR swizzle (inverse on source)
    gsrc[j] = (isA ? xb + (size_t)(rowBase + row) * 1024
                   : wt + (size_t)(colBase + row) * 1024) + ssl * 8;
    ldst[j] = (isA ? (char*)As : (char*)Bs) + idx * 16;
  }

#define STG(buf, kt0) do {                                                                \
    _Pragma("unroll")                                                                     \
    for (int j_ = 0; j_ < 4; ++j_)                                                        \
      if (j_ < nL)                                                                        \
        __builtin_amdgcn_global_load_lds(                                                 \
            (const __attribute__((address_space(1))) void*)(gsrc[j_] + (kt0) * 64),       \
            (__attribute__((address_space(3))) void*)(ldst[j_] + (buf) * bstr), 16, 0, 0);\
  } while (0)

#define VMW_STEADY() do {                                                                 \
    if (isA) asm volatile("s_waitcnt vmcnt(4)" ::: "memory");                             \
    else     asm volatile("s_waitcnt vmcnt(3)" ::: "memory");                             \
  } while (0)
#define VMCNT0() asm volatile("s_waitcnt vmcnt(0)" ::: "memory")
#define LGKM0()  asm volatile("s_waitcnt lgkmcnt(0)" ::: "memory")
#define BAR()    __builtin_amdgcn_s_barrier()

  f32x4 acc[2][4] = {};
  const int fs0 = khalf ^ (fr & 7);   // swizzled slot for ks=0; ks=1 is fs0^4

#define LOAD_FRAGS(cur, af, bff) do {                                                     \
    _Pragma("unroll")                                                                     \
    for (int m = 0; m < 2; ++m) {                                                         \
      const unsigned short* r = &As[cur][wr * 32 + m * 16 + fr][0];                       \
      af[m][0] = *(const bf16x8*)(r + fs0 * 8);                                           \
      af[m][1] = *(const bf16x8*)(r + (fs0 ^ 4) * 8);                                     \
    }                                                                                     \
    _Pragma("unroll")                                                                     \
    for (int n = 0; n < 4; ++n) {                                                         \
      const unsigned short* r = &Bs[cur][wc * 64 + n * 16 + fr][0];                       \
      bff[n][0] = *(const bf16x8*)(r + fs0 * 8);                                          \
      bff[n][1] = *(const bf16x8*)(r + (fs0 ^ 4) * 8);                                    \
    }                                                                                     \
  } while (0)

#define DO_MFMA(af, bff) do {                                                             \
    _Pragma("unroll")                                                                     \
    for (int m = 0; m < 2; ++m)                                                           \
      _Pragma("unroll")                                                                   \
      for (int n = 0; n < 4; ++n) {                                                       \
        acc[m][n] = __builtin_amdgcn_mfma_f32_16x16x32_bf16(af[m][0], bff[n][0], acc[m][n], 0, 0, 0); \
        acc[m][n] = __builtin_amdgcn_mfma_f32_16x16x32_bf16(af[m][1], bff[n][1], acc[m][n], 0, 0, 0); \
      }                                                                                   \
  } while (0)

  STG(0, 0);
  STG(1, 1);
#pragma unroll 1
  for (int ktile = 0; ktile < 16; ++ktile) {
    const int cur = ktile % 3;
    if (ktile < 15) { VMW_STEADY(); }   // tile `ktile` landed; tile ktile+1 in flight
    else            { VMCNT0(); }
    BAR();                              // all waves consumed buf[(ktile-1)%3] last iter
    __builtin_amdgcn_sched_barrier(0);
    bf16x8 af[2][2], bff[4][2];
    LOAD_FRAGS(cur, af, bff);           // issue ds_reads first (lgkm wait starts earlier)
    if (ktile < 14) STG((ktile + 2) % 3, ktile + 2);   // overwrites the consumed buffer
    LGKM0();                            // my ds_reads complete (values in regs)
    __builtin_amdgcn_sched_barrier(0);
    __builtin_amdgcn_s_setprio(1);
    DO_MFMA(af, bff);
    __builtin_amdgcn_s_setprio(0);
  }
#undef STG
#undef LOAD_FRAGS
#undef DO_MFMA

  // ---- fused epilogue (R4/R8-verified: per wave 32 rows x one 64-col head span) ----
  const int g2 = khalf;               // C row group: row = 4*g2+i
  const int ocol = lane & 15;         // C col within 16-block
  const int col0 = colBase + wc * 64; // this wave's 64-col span = one head-region
  const int region = col0 >> 10;      // 0=q 1=v 2=k
  const int h = (col0 & 1023) >> 6;
  const int r0 = rowBase + wr * 32;   // global token base of this wave
  const int cch = r0 >> 6;            // chunk index
  const int lbase = (wr & 1) * 32;    // chunk-local row base
  float bv[4];
#pragma unroll
  for (int n = 0; n < 4; ++n) bv[n] = bias[col0 + 16 * n + ocol];

  if (region == 0) {                  // q: softmax over e (in-wave), *0.125
#pragma unroll
    for (int m = 0; m < 2; ++m) {
#pragma unroll
      for (int i = 0; i < 4; ++i) {
        float v[4];
#pragma unroll
        for (int n = 0; n < 4; ++n) v[n] = acc[m][n][i] + bv[n];
        float mx = fmaxf(fmaxf(v[0], v[1]), fmaxf(v[2], v[3]));
#pragma unroll
        for (int off = 1; off <= 8; off <<= 1) mx = fmaxf(mx, __shfl_xor(mx, off));
        float s = 0.f;
#pragma unroll
        for (int n = 0; n < 4; ++n) { v[n] = __expf(v[n] - mx); s += v[n]; }
#pragma unroll
        for (int off = 1; off <= 8; off <<= 1) s += __shfl_xor(s, off);
        float inv = 0.125f / s;
        int tok = r0 + 16 * m + 4 * g2 + i;
        unsigned short* qrow = qh + ((size_t)h * NTOK + tok) * 64;
#pragma unroll
        for (int n = 0; n < 4; ++n) qrow[16 * n + ocol] = f2bf(v[n] * inv);
      }
    }
  } else if (region == 1) {           // v: write transposed vt[h][c][e][tok]
    unsigned short* vb = vt + (size_t)(h * NCH + cch) * 4096;
#pragma unroll
    for (int m = 0; m < 2; ++m) {
      int tl = lbase + 16 * m + 4 * g2;
#pragma unroll
      for (int n = 0; n < 4; ++n) {
        int e = 16 * n + ocol;
        ushort4 p = { f2bf(acc[m][n][0] + bv[n]), f2bf(acc[m][n][1] + bv[n]),
                      f2bf(acc[m][n][2] + bv[n]), f2bf(acc[m][n][3] + bv[n]) };
        *(ushort4*)&vb[(size_t)e * 64 + tl] = p;
      }
    }
  } else {                            // k: exp, write kh row-major + kt transposed
    unsigned short* kb = kt + (size_t)(h * NCH + cch) * 4096;
#pragma unroll
    for (int m = 0; m < 2; ++m) {
      int tl = lbase + 16 * m + 4 * g2;
#pragma unroll
      for (int n = 0; n < 4; ++n) {
        int e = 16 * n + ocol;
        float kv[4];
#pragma unroll
        for (int i = 0; i < 4; ++i) kv[i] = __expf(acc[m][n][i] + bv[n]);
        ushort4 p = { f2bf(kv[0]), f2bf(kv[1]), f2bf(kv[2]), f2bf(kv[3]) };
        *(ushort4*)&kb[(size_t)e * 64 + tl] = p;
#pragma unroll
        for (int i = 0; i < 4; ++i)
          kh[((size_t)h * NTOK + r0 + 16 * m + 4 * g2 + i) * 64 + e] = p[i];
      }
    }
  }
}

// ---- per-(h,c) chunk sums via MFMA: stored bf16 as ScT[e'][d]; z[d] f32 ----
__global__ __launch_bounds__(256) void k_chunk_sums(const unsigned short* __restrict__ kt,
                                                    const unsigned short* __restrict__ vt,
                                                    unsigned short* __restrict__ Sc,
                                                    float* __restrict__ zc) {
  int h = blockIdx.x >> 5, c = blockIdx.x & 31;
  __shared__ __align__(16) unsigned short Kt[64][72], Vt[64][72];
  int t = threadIdx.x, lane = t & 63, w = t >> 6;
  int fr = lane & 15, g = lane >> 4, fko = g * 8;
  const unsigned short* kg = kt + (size_t)(h * NCH + c) * 4096;
  const unsigned short* vg = vt + (size_t)(h * NCH + c) * 4096;
  for (int s = t; s < 512; s += 256) {
    int r = s >> 3, c8 = (s & 7) * 8;
    *(ushort8v*)&Kt[r][c8] = *(const ushort8v*)&kg[r * 64 + c8];
    *(ushort8v*)&Vt[r][c8] = *(const ushort8v*)&vg[r * 64 + c8];
  }
  __syncthreads();
  bf16x8 ka[2];
#pragma unroll
  for (int ks = 0; ks < 2; ++ks) ka[ks] = *(const bf16x8*)&Kt[16 * w + fr][32 * ks + fko];
  f32x4 s4[4] = {};
#pragma unroll
  for (int nb = 0; nb < 4; ++nb)
#pragma unroll
    for (int ks = 0; ks < 2; ++ks) {
      bf16x8 vf = *(const bf16x8*)&Vt[16 * nb + fr][32 * ks + fko];
      s4[nb] = __builtin_amdgcn_mfma_f32_16x16x32_bf16(ka[ks], vf, s4[nb], 0, 0, 0);
    }
  unsigned short* so = Sc + (size_t)(h * NCH + c) * 4096;   // [e'][d] bf16
#pragma unroll
  for (int nb = 0; nb < 4; ++nb) {
    ushort4 o = { f2bf(s4[nb][0]), f2bf(s4[nb][1]), f2bf(s4[nb][2]), f2bf(s4[nb][3]) };
    *(ushort4*)&so[(size_t)(16 * nb + fr) * 64 + 16 * w + 4 * g] = o;
  }
  if (w == 0) {
    float z = 0.f;
#pragma unroll
    for (int j = 0; j < 8; ++j) {
      bf16x8 kv = *(const bf16x8*)&Kt[lane][j * 8];
#pragma unroll
      for (int e = 0; e < 8; ++e) z += bf2f((unsigned short)kv[e]);
    }
    zc[(size_t)(h * NCH + c) * 64 + lane] = z;
  }
}

// ---- exclusive prefix over chunks, element-parallel; bf16 in, bf16 out (f32 accum) ----
__global__ __launch_bounds__(256) void k_scan(const unsigned short* __restrict__ Sc,
                                              unsigned short* __restrict__ Sp,
                                              const float* __restrict__ zc,
                                              float* __restrict__ zp) {
  int b = blockIdx.x;
  if (b < 256) {
    int tg = b * 256 + threadIdx.x;
    int h = tg >> 12, e = tg & 4095;
    float run = 0.f;
    for (int c = 0; c < NCH; ++c) {
      size_t idx = (size_t)(h * NCH + c) * 4096 + e;
      float v = bf2f(Sc[idx]);
      Sp[idx] = f2bf(run);
      run += v;
    }
  } else {
#pragma unroll
    for (int j = 0; j < 4; ++j) {
      int s = threadIdx.x + j * 256;
      int h = s >> 6, d = s & 63;
      float run = 0.f;
      for (int c = 0; c < NCH; ++c) {
        size_t idx = (size_t)(h * NCH + c) * 64 + d;
        zp[idx] = run;
        run += zc[idx];
      }
    }
  }
}

// ---- attention: O = M(QK^T) V + Q S_prev, denom fused; all MFMA ----
__global__ __launch_bounds__(256) void k_attn(const unsigned short* __restrict__ qh,
                                              const unsigned short* __restrict__ kh,
                                              const unsigned short* __restrict__ vt,
                                              const unsigned short* __restrict__ Sp,
                                              const float* __restrict__ zp,
                                              float* __restrict__ out) {
  int h = blockIdx.x >> 5, c = blockIdx.x & 31;
  __shared__ __align__(16) unsigned short Qs[64][72], Ks[64][72], Vts[64][72], Sts[64][72], Ams[64][72];
  __shared__ __align__(16) float zs[64];
  __shared__ float denom[64];
  int t = threadIdx.x, lane = t & 63, w = t >> 6;
  int fr = lane & 15, g = lane >> 4, fko = g * 8;
  const unsigned short* qg = qh + ((size_t)h * NTOK + c * 64) * 64;
  const unsigned short* kg = kh + ((size_t)h * NTOK + c * 64) * 64;
  const unsigned short* vg = vt + (size_t)(h * NCH + c) * 4096;
  const unsigned short* sg = Sp + (size_t)(h * NCH + c) * 4096;
  for (int s = t; s < 512; s += 256) {
    int r = s >> 3, c8 = (s & 7) * 8;
    *(ushort8v*)&Qs[r][c8]  = *(const ushort8v*)&qg[r * 64 + c8];
    *(ushort8v*)&Ks[r][c8]  = *(const ushort8v*)&kg[r * 64 + c8];
    *(ushort8v*)&Vts[r][c8] = *(const ushort8v*)&vg[r * 64 + c8];
    *(ushort8v*)&Sts[r][c8] = *(const ushort8v*)&sg[r * 64 + c8];
  }
  if (t < 64) zs[t] = zp[(size_t)(h * NCH + c) * 64 + t];
  __syncthreads();

  // step 1: A = Q K^T
  bf16x8 qa[2];
#pragma unroll
  for (int ks = 0; ks < 2; ++ks) qa[ks] = *(const bf16x8*)&Qs[16 * w + fr][32 * ks + fko];
  f32x4 a1[4] = {};
#pragma unroll
  for (int mb = 0; mb < 4; ++mb)
#pragma unroll
    for (int ks = 0; ks < 2; ++ks) {
      bf16x8 kf = *(const bf16x8*)&Ks[16 * mb + fr][32 * ks + fko];
      a1[mb] = __builtin_amdgcn_mfma_f32_16x16x32_bf16(qa[ks], kf, a1[mb], 0, 0, 0);
    }
#pragma unroll
  for (int i = 0; i < 4; ++i) {
    int n = 16 * w + 4 * g + i;
    ushort4 qv4 = *(const ushort4*)&Qs[n][fr * 4];
    float4  zv4 = *(const float4*)&zs[fr * 4];
    float rs = bf2f(qv4.x) * zv4.x + bf2f(qv4.y) * zv4.y +
               bf2f(qv4.z) * zv4.z + bf2f(qv4.w) * zv4.w;
#pragma unroll
    for (int mb = 0; mb < 4; ++mb) {
      int m = 16 * mb + fr;
      float v = (m <= n) ? a1[mb][i] : 0.f;
      a1[mb][i] = v;
      rs += v;
      Ams[n][16 * mb + fr] = f2bf(v);
    }
#pragma unroll
    for (int off = 1; off <= 8; off <<= 1) rs += __shfl_xor(rs, off);
    if (fr == 0) denom[n] = rs + 1.25e-7f;   // eps * sum(q) = 1e-6 * 0.125
  }
  __syncthreads();

  // step 2: O^T[e'][n] = Vt·A + St·Q
  bf16x8 xa[4];
#pragma unroll
  for (int ks = 0; ks < 2; ++ks) {
    xa[ks]     = *(const bf16x8*)&Vts[16 * w + fr][32 * ks + fko];
    xa[2 + ks] = *(const bf16x8*)&Sts[16 * w + fr][32 * ks + fko];
  }
  f32x4 o4[4] = {};
#pragma unroll
  for (int nb = 0; nb < 4; ++nb)
#pragma unroll
    for (int ks = 0; ks < 2; ++ks) {
      bf16x8 afr = *(const bf16x8*)&Ams[16 * nb + fr][32 * ks + fko];
      o4[nb] = __builtin_amdgcn_mfma_f32_16x16x32_bf16(xa[ks], afr, o4[nb], 0, 0, 0);
      bf16x8 qfr = *(const bf16x8*)&Qs[16 * nb + fr][32 * ks + fko];
      o4[nb] = __builtin_amdgcn_mfma_f32_16x16x32_bf16(xa[2 + ks], qfr, o4[nb], 0, 0, 0);
    }
#pragma unroll
  for (int nb = 0; nb < 4; ++nb) {
    int n = 16 * nb + fr;
    float dv = denom[n];
    float4 res = { o4[nb][0] / dv, o4[nb][1] / dv, o4[nb][2] / dv, o4[nb][3] / dv };
    *(float4*)&out[(size_t)(c * 64 + n) * 1024 + h * 64 + 16 * w + 4 * g] = res;
  }
}

extern "C" void kernel_launch(void* const* d_in, const int* in_sizes, int n_in,
                              void* d_out, int out_size, void* d_ws, size_t ws_size,
                              hipStream_t stream) {
  (void)in_sizes; (void)n_in; (void)out_size; (void)ws_size;
  const float* x = (const float*)d_in[0];
  const float* W = (const float*)d_in[1];
  const float* b = (const float*)d_in[2];
  char* ws = (char*)d_ws;

  const size_t MB = 1024 * 1024;
  unsigned short* xb = (unsigned short*)(ws + 0);        // 4 MB
  unsigned short* Wt = (unsigned short*)(ws + 4 * MB);   // 6 MB
  unsigned short* qh = (unsigned short*)(ws + 10 * MB);  // 4 MB
  unsigned short* kh = (unsigned short*)(ws + 14 * MB);  // 4 MB
  unsigned short* kt = (unsigned short*)(ws + 18 * MB);  // 4 MB
  unsigned short* vt = (unsigned short*)(ws + 22 * MB);  // 4 MB
  unsigned short* Sc = (unsigned short*)(ws + 26 * MB);  // 4 MB (bf16 chunk sums)
  unsigned short* Sp = (unsigned short*)(ws + 30 * MB);  // 4 MB (bf16 exclusive prefix)
  float*          zc = (float*)(ws + 34 * MB);           // 128 KB
  float*          zp = (float*)(ws + 34 * MB + 131072);  // 128 KB

  k_prep_inputs<<<dim3(5120), dim3(256), 0, stream>>>(x, xb, W, Wt);
  k_gemm_fused<<<dim3(16, 16), dim3(768), 0, stream>>>(xb, Wt, b, qh, kh, kt, vt);
  k_chunk_sums<<<dim3(512), dim3(256), 0, stream>>>(kt, vt, Sc, zc);
  k_scan<<<dim3(257), dim3(256), 0, stream>>>(Sc, Sp, zc, zp);
  k_attn<<<dim3(512), dim3(256), 0, stream>>>(qh, kh, vt, Sp, zp, (float*)d_out);
}

// Round 16
// 44.322 us; speedup vs baseline: 1.4323x; 1.0453x over previous
//
#include <hip/hip_runtime.h>
#include <stdint.h>

// B=1, N=2048, D=1024, h=16, e=64; chunks of 64 tokens -> 32 chunks/head
#define NTOK 2048
#define NCH 32

typedef __attribute__((ext_vector_type(8))) short bf16x8;
typedef __attribute__((ext_vector_type(8))) unsigned short ushort8v;
typedef __attribute__((ext_vector_type(4))) float f32x4;

__device__ __forceinline__ unsigned short f2bf(float f) {
  unsigned u = __float_as_uint(f);
  u += 0x7fffu + ((u >> 16) & 1u);   // RNE
  return (unsigned short)(u >> 16);
}
__device__ __forceinline__ float bf2f(unsigned short s) {
  return __uint_as_float(((unsigned)s) << 16);
}

// ---- fused input prep: x -> bf16; W -> Wt bf16 transposed + HEAD-MAJOR permuted ----
// Wt row layout: [head h][q(64) | v(64) | k(64)]  (row = 192h + 64*region + j)
__global__ __launch_bounds__(256) void k_prep_inputs(const float* __restrict__ x,
                                                     unsigned short* __restrict__ xb,
                                                     const float* __restrict__ W,
                                                     unsigned short* __restrict__ Wt) {
  int bid = blockIdx.x;
  if (bid < 2048) {
    int i = (bid * 256 + threadIdx.x) * 4;
    float4 v = *(const float4*)(x + i);
    ushort4 o = { f2bf(v.x), f2bf(v.y), f2bf(v.z), f2bf(v.w) };
    *(ushort4*)(xb + i) = o;
  } else {
    __shared__ float tile[32][33];
    int id = bid - 2048;            // 3072 blocks: bx in [0,96), by in [0,32)
    int bx = id % 96, by = id / 96;
    int tx = threadIdx.x & 31, ty = threadIdx.x >> 5;
    int c0 = bx * 32;
    int r0 = by * 32;
#pragma unroll
    for (int j = 0; j < 32; j += 8)
      tile[ty + j][tx] = W[(size_t)(r0 + ty + j) * 3072 + c0 + tx];
    __syncthreads();
#pragma unroll
    for (int j = 0; j < 32; j += 8) {
      int oc = c0 + ty + j;          // original W column
      int rowp = ((oc & 1023) >> 6) * 192 + (oc >> 10) * 64 + (oc & 63);
      Wt[(size_t)rowp * 1024 + r0 + tx] = f2bf(tile[tx][ty + j]);
    }
  }
}

// ---- GEMM 2048x3072 (head-major Wt), 128x192 tile, 768 thr (12 waves of 32x64), BK=64 ----
// R14/R15-verified 3-buffer single-barrier counted-vmcnt loop. Block (bx,by) = head bx,
// chunks {2by, 2by+1}: q,v,k of one head are block-local -> chunk sums S_c = K_c^T V_c
// computed in-kernel on LDS tiles (aliased onto As; [64][72] pad); kt buffer eliminated.
__global__ __launch_bounds__(768, 1) void k_gemm_fused(const unsigned short* __restrict__ xb,
                                                       const unsigned short* __restrict__ wt,
                                                       const float* __restrict__ bias,
                                                       unsigned short* __restrict__ qh,
                                                       unsigned short* __restrict__ kh,
                                                       unsigned short* __restrict__ vt,
                                                       unsigned short* __restrict__ Sc,
                                                       float* __restrict__ zc) {
  __shared__ __align__(16) unsigned short As[3][128][64];    // 3 x 16 KB (reused for K/V tiles)
  __shared__ __align__(16) unsigned short Bs[3][192][64];    // 3 x 24 KB
  const int t = threadIdx.x;           // 0..767
  const int lane = t & 63;
  const int wave = t >> 6;             // 0..11
  const int wr = wave / 3;             // 0..3 (32-row block)
  const int wc = wave % 3;             // 0..2 (64-col block) == region (q/v/k)
  const int rowBase = blockIdx.y * 128;
  const int colBase = blockIdx.x * 192;
  const int fr = lane & 15;
  const int khalf = lane >> 4;         // 0..3

  // staging: A = 1024 chunks over threads 0..255 (4 each); B = 1536 over 256..767 (3 each)
  const bool isA = t < 256;            // wave-uniform
  const int nL = isA ? 4 : 3;
  const int bstr = isA ? 16384 : 24576;
  const unsigned short* gsrc[4];
  char* ldst[4];
#pragma unroll
  for (int j = 0; j < 4; ++j) {
    int idx = isA ? (t + j * 256) : (t - 256 + j * 512);
    if (j >= nL) idx = 0;
    int row = idx >> 3;
    int ssl = (idx & 7) ^ (row & 7);   // XOR swizzle (inverse on source)
    gsrc[j] = (isA ? xb + (size_t)(rowBase + row) * 1024
                   : wt + (size_t)(colBase + row) * 1024) + ssl * 8;
    ldst[j] = (isA ? (char*)As : (char*)Bs) + idx * 16;
  }

#define STG(buf, kt0) do {                                                                \
    _Pragma("unroll")                                                                     \
    for (int j_ = 0; j_ < 4; ++j_)                                                        \
      if (j_ < nL)                                                                        \
        __builtin_amdgcn_global_load_lds(                                                 \
            (const __attribute__((address_space(1))) void*)(gsrc[j_] + (kt0) * 64),       \
            (__attribute__((address_space(3))) void*)(ldst[j_] + (buf) * bstr), 16, 0, 0);\
  } while (0)

#define VMW_STEADY() do {                                                                 \
    if (isA) asm volatile("s_waitcnt vmcnt(4)" ::: "memory");                             \
    else     asm volatile("s_waitcnt vmcnt(3)" ::: "memory");                             \
  } while (0)
#define VMCNT0() asm volatile("s_waitcnt vmcnt(0)" ::: "memory")
#define LGKM0()  asm volatile("s_waitcnt lgkmcnt(0)" ::: "memory")
#define BAR()    __builtin_amdgcn_s_barrier()

  f32x4 acc[2][4] = {};
  const int fs0 = khalf ^ (fr & 7);   // swizzled slot for ks=0; ks=1 is fs0^4

#define LOAD_FRAGS(cur, af, bff) do {                                                     \
    _Pragma("unroll")                                                                     \
    for (int m = 0; m < 2; ++m) {                                                         \
      const unsigned short* r = &As[cur][wr * 32 + m * 16 + fr][0];                       \
      af[m][0] = *(const bf16x8*)(r + fs0 * 8);                                           \
      af[m][1] = *(const bf16x8*)(r + (fs0 ^ 4) * 8);                                     \
    }                                                                                     \
    _Pragma("unroll")                                                                     \
    for (int n = 0; n < 4; ++n) {                                                         \
      const unsigned short* r = &Bs[cur][wc * 64 + n * 16 + fr][0];                       \
      bff[n][0] = *(const bf16x8*)(r + fs0 * 8);                                          \
      bff[n][1] = *(const bf16x8*)(r + (fs0 ^ 4) * 8);                                    \
    }                                                                                     \
  } while (0)

#define DO_MFMA(af, bff) do {                                                             \
    _Pragma("unroll")                                                                     \
    for (int m = 0; m < 2; ++m)                                                           \
      _Pragma("unroll")                                                                   \
      for (int n = 0; n < 4; ++n) {                                                       \
        acc[m][n] = __builtin_amdgcn_mfma_f32_16x16x32_bf16(af[m][0], bff[n][0], acc[m][n], 0, 0, 0); \
        acc[m][n] = __builtin_amdgcn_mfma_f32_16x16x32_bf16(af[m][1], bff[n][1], acc[m][n], 0, 0, 0); \
      }                                                                                   \
  } while (0)

  STG(0, 0);
  STG(1, 1);
#pragma unroll 1
  for (int ktile = 0; ktile < 16; ++ktile) {
    const int cur = ktile % 3;
    if (ktile < 15) { VMW_STEADY(); }
    else            { VMCNT0(); }
    BAR();
    __builtin_amdgcn_sched_barrier(0);
    bf16x8 af[2][2], bff[4][2];
    LOAD_FRAGS(cur, af, bff);
    if (ktile < 14) STG((ktile + 2) % 3, ktile + 2);
    LGKM0();
    __builtin_amdgcn_sched_barrier(0);
    __builtin_amdgcn_s_setprio(1);
    DO_MFMA(af, bff);
    __builtin_amdgcn_s_setprio(0);
  }
#undef STG
#undef LOAD_FRAGS
#undef DO_MFMA

  // all waves' As reads are drained (each passed its own LGKM0) -> safe to alias As
  BAR();
  unsigned short (*Lkv)[2][64][72] =
      reinterpret_cast<unsigned short (*)[2][64][72]>(&As[0][0][0]);  // [chunk][k/v][e][tok]

  // ---- fused epilogue: region = wc, head = blockIdx.x ----
  const int g2 = khalf;               // C row group: row = 4*g2+i
  const int ocol = lane & 15;         // C col within 16-block
  const int region = wc;              // 0=q 1=v 2=k
  const int h = blockIdx.x;
  const int r0 = rowBase + wr * 32;   // global token base of this wave
  const int cch = r0 >> 6;            // chunk index
  const int cq = wr >> 1;             // chunk-local (0/1) within block
  const int lbase = (wr & 1) * 32;    // chunk-local row base
  float bv[4];
#pragma unroll
  for (int n = 0; n < 4; ++n) bv[n] = bias[region * 1024 + h * 64 + 16 * n + ocol];

  if (region == 0) {                  // q: softmax over e (in-wave), *0.125
#pragma unroll
    for (int m = 0; m < 2; ++m) {
#pragma unroll
      for (int i = 0; i < 4; ++i) {
        float v[4];
#pragma unroll
        for (int n = 0; n < 4; ++n) v[n] = acc[m][n][i] + bv[n];
        float mx = fmaxf(fmaxf(v[0], v[1]), fmaxf(v[2], v[3]));
#pragma unroll
        for (int off = 1; off <= 8; off <<= 1) mx = fmaxf(mx, __shfl_xor(mx, off));
        float s = 0.f;
#pragma unroll
        for (int n = 0; n < 4; ++n) { v[n] = __expf(v[n] - mx); s += v[n]; }
#pragma unroll
        for (int off = 1; off <= 8; off <<= 1) s += __shfl_xor(s, off);
        float inv = 0.125f / s;
        int tok = r0 + 16 * m + 4 * g2 + i;
        unsigned short* qrow = qh + ((size_t)h * NTOK + tok) * 64;
#pragma unroll
        for (int n = 0; n < 4; ++n) qrow[16 * n + ocol] = f2bf(v[n] * inv);
      }
    }
  } else if (region == 1) {           // v: write vt global + LDS tile
    unsigned short* vb = vt + (size_t)(h * NCH + cch) * 4096;
#pragma unroll
    for (int m = 0; m < 2; ++m) {
      int tl = lbase + 16 * m + 4 * g2;
#pragma unroll
      for (int n = 0; n < 4; ++n) {
        int e = 16 * n + ocol;
        ushort4 p = { f2bf(acc[m][n][0] + bv[n]), f2bf(acc[m][n][1] + bv[n]),
                      f2bf(acc[m][n][2] + bv[n]), f2bf(acc[m][n][3] + bv[n]) };
        *(ushort4*)&vb[(size_t)e * 64 + tl] = p;
        *(ushort4*)&Lkv[cq][1][e][tl] = p;
      }
    }
  } else {                            // k: exp, write kh global + LDS tile
#pragma unroll
    for (int m = 0; m < 2; ++m) {
      int tl = lbase + 16 * m + 4 * g2;
#pragma unroll
      for (int n = 0; n < 4; ++n) {
        int e = 16 * n + ocol;
        float kv[4];
#pragma unroll
        for (int i = 0; i < 4; ++i) kv[i] = __expf(acc[m][n][i] + bv[n]);
        ushort4 p = { f2bf(kv[0]), f2bf(kv[1]), f2bf(kv[2]), f2bf(kv[3]) };
        *(ushort4*)&Lkv[cq][0][e][tl] = p;
#pragma unroll
        for (int i = 0; i < 4; ++i)
          kh[((size_t)h * NTOK + r0 + 16 * m + 4 * g2 + i) * 64 + e] = p[i];
      }
    }
  }
  BAR();   // K/V LDS tiles complete

  // ---- in-block chunk sums (verbatim k_chunk_sums body on LDS tiles) ----
  if (wave < 8) {
    const int q = wave >> 2;          // chunk-local 0/1
    const int w4 = wave & 3;          // d-block
    const int cchg = 2 * blockIdx.y + q;
    bf16x8 ka[2];
#pragma unroll
    for (int ks = 0; ks < 2; ++ks)
      ka[ks] = *(const bf16x8*)&Lkv[q][0][16 * w4 + fr][32 * ks + khalf * 8];
    f32x4 s4[4] = {};
#pragma unroll
    for (int nb = 0; nb < 4; ++nb)
#pragma unroll
      for (int ks = 0; ks < 2; ++ks) {
        bf16x8 vf = *(const bf16x8*)&Lkv[q][1][16 * nb + fr][32 * ks + khalf * 8];
        s4[nb] = __builtin_amdgcn_mfma_f32_16x16x32_bf16(ka[ks], vf, s4[nb], 0, 0, 0);
      }
    unsigned short* so = Sc + (size_t)(h * NCH + cchg) * 4096;   // [e'][d] bf16
#pragma unroll
    for (int nb = 0; nb < 4; ++nb) {
      ushort4 o = { f2bf(s4[nb][0]), f2bf(s4[nb][1]), f2bf(s4[nb][2]), f2bf(s4[nb][3]) };
      *(ushort4*)&so[(size_t)(16 * nb + fr) * 64 + 16 * w4 + 4 * g2] = o;
    }
    if (w4 == 0) {
      float z = 0.f;
#pragma unroll
      for (int j = 0; j < 8; ++j) {
        bf16x8 kv = *(const bf16x8*)&Lkv[q][0][lane][j * 8];
#pragma unroll
        for (int e = 0; e < 8; ++e) z += bf2f((unsigned short)kv[e]);
      }
      zc[(size_t)(h * NCH + cchg) * 64 + lane] = z;
    }
  }
}

// ---- exclusive prefix over chunks, element-parallel; bf16 in, bf16 out (f32 accum) ----
__global__ __launch_bounds__(256) void k_scan(const unsigned short* __restrict__ Sc,
                                              unsigned short* __restrict__ Sp,
                                              const float* __restrict__ zc,
                                              float* __restrict__ zp) {
  int b = blockIdx.x;
  if (b < 256) {
    int tg = b * 256 + threadIdx.x;
    int h = tg >> 12, e = tg & 4095;
    float run = 0.f;
    for (int c = 0; c < NCH; ++c) {
      size_t idx = (size_t)(h * NCH + c) * 4096 + e;
      float v = bf2f(Sc[idx]);
      Sp[idx] = f2bf(run);
      run += v;
    }
  } else {
#pragma unroll
    for (int j = 0; j < 4; ++j) {
      int s = threadIdx.x + j * 256;
      int h = s >> 6, d = s & 63;
      float run = 0.f;
      for (int c = 0; c < NCH; ++c) {
        size_t idx = (size_t)(h * NCH + c) * 64 + d;
        zp[idx] = run;
        run += zc[idx];
      }
    }
  }
}

// ---- attention: O = M(QK^T) V + Q S_prev, denom fused; all MFMA ----
__global__ __launch_bounds__(256) void k_attn(const unsigned short* __restrict__ qh,
                                              const unsigned short* __restrict__ kh,
                                              const unsigned short* __restrict__ vt,
                                              const unsigned short* __restrict__ Sp,
                                              const float* __restrict__ zp,
                                              float* __restrict__ out) {
  int h = blockIdx.x >> 5, c = blockIdx.x & 31;
  __shared__ __align__(16) unsigned short Qs[64][72], Ks[64][72], Vts[64][72], Sts[64][72], Ams[64][72];
  __shared__ __align__(16) float zs[64];
  __shared__ float denom[64];
  int t = threadIdx.x, lane = t & 63, w = t >> 6;
  int fr = lane & 15, g = lane >> 4, fko = g * 8;
  const unsigned short* qg = qh + ((size_t)h * NTOK + c * 64) * 64;
  const unsigned short* kg = kh + ((size_t)h * NTOK + c * 64) * 64;
  const unsigned short* vg = vt + (size_t)(h * NCH + c) * 4096;
  const unsigned short* sg = Sp + (size_t)(h * NCH + c) * 4096;
  for (int s = t; s < 512; s += 256) {
    int r = s >> 3, c8 = (s & 7) * 8;
    *(ushort8v*)&Qs[r][c8]  = *(const ushort8v*)&qg[r * 64 + c8];
    *(ushort8v*)&Ks[r][c8]  = *(const ushort8v*)&kg[r * 64 + c8];
    *(ushort8v*)&Vts[r][c8] = *(const ushort8v*)&vg[r * 64 + c8];
    *(ushort8v*)&Sts[r][c8] = *(const ushort8v*)&sg[r * 64 + c8];
  }
  if (t < 64) zs[t] = zp[(size_t)h * NCH * 64 + (size_t)c * 64 + t];
  __syncthreads();

  // step 1: A = Q K^T
  bf16x8 qa[2];
#pragma unroll
  for (int ks = 0; ks < 2; ++ks) qa[ks] = *(const bf16x8*)&Qs[16 * w + fr][32 * ks + fko];
  f32x4 a1[4] = {};
#pragma unroll
  for (int mb = 0; mb < 4; ++mb)
#pragma unroll
    for (int ks = 0; ks < 2; ++ks) {
      bf16x8 kf = *(const bf16x8*)&Ks[16 * mb + fr][32 * ks + fko];
      a1[mb] = __builtin_amdgcn_mfma_f32_16x16x32_bf16(qa[ks], kf, a1[mb], 0, 0, 0);
    }
#pragma unroll
  for (int i = 0; i < 4; ++i) {
    int n = 16 * w + 4 * g + i;
    ushort4 qv4 = *(const ushort4*)&Qs[n][fr * 4];
    float4  zv4 = *(const float4*)&zs[fr * 4];
    float rs = bf2f(qv4.x) * zv4.x + bf2f(qv4.y) * zv4.y +
               bf2f(qv4.z) * zv4.z + bf2f(qv4.w) * zv4.w;
#pragma unroll
    for (int mb = 0; mb < 4; ++mb) {
      int m = 16 * mb + fr;
      float v = (m <= n) ? a1[mb][i] : 0.f;
      a1[mb][i] = v;
      rs += v;
      Ams[n][16 * mb + fr] = f2bf(v);
    }
#pragma unroll
    for (int off = 1; off <= 8; off <<= 1) rs += __shfl_xor(rs, off);
    if (fr == 0) denom[n] = rs + 1.25e-7f;   // eps * sum(q) = 1e-6 * 0.125
  }
  __syncthreads();

  // step 2: O^T[e'][n] = Vt·A + St·Q
  bf16x8 xa[4];
#pragma unroll
  for (int ks = 0; ks < 2; ++ks) {
    xa[ks]     = *(const bf16x8*)&Vts[16 * w + fr][32 * ks + fko];
    xa[2 + ks] = *(const bf16x8*)&Sts[16 * w + fr][32 * ks + fko];
  }
  f32x4 o4[4] = {};
#pragma unroll
  for (int nb = 0; nb < 4; ++nb)
#pragma unroll
    for (int ks = 0; ks < 2; ++ks) {
      bf16x8 afr = *(const bf16x8*)&Ams[16 * nb + fr][32 * ks + fko];
      o4[nb] = __builtin_amdgcn_mfma_f32_16x16x32_bf16(xa[ks], afr, o4[nb], 0, 0, 0);
      bf16x8 qfr = *(const bf16x8*)&Qs[16 * nb + fr][32 * ks + fko];
      o4[nb] = __builtin_amdgcn_mfma_f32_16x16x32_bf16(xa[2 + ks], qfr, o4[nb], 0, 0, 0);
    }
#pragma unroll
  for (int nb = 0; nb < 4; ++nb) {
    int n = 16 * nb + fr;
    float dv = denom[n];
    float4 res = { o4[nb][0] / dv, o4[nb][1] / dv, o4[nb][2] / dv, o4[nb][3] / dv };
    *(float4*)&out[(size_t)(c * 64 + n) * 1024 + h * 64 + 16 * w + 4 * g] = res;
  }
}

extern "C" void kernel_launch(void* const* d_in, const int* in_sizes, int n_in,
                              void* d_out, int out_size, void* d_ws, size_t ws_size,
                              hipStream_t stream) {
  (void)in_sizes; (void)n_in; (void)out_size; (void)ws_size;
  const float* x = (const float*)d_in[0];
  const float* W = (const float*)d_in[1];
  const float* b = (const float*)d_in[2];
  char* ws = (char*)d_ws;

  const size_t MB = 1024 * 1024;
  unsigned short* xb = (unsigned short*)(ws + 0);        // 4 MB
  unsigned short* Wt = (unsigned short*)(ws + 4 * MB);   // 6 MB
  unsigned short* qh = (unsigned short*)(ws + 10 * MB);  // 4 MB
  unsigned short* kh = (unsigned short*)(ws + 14 * MB);  // 4 MB
  unsigned short* vt = (unsigned short*)(ws + 18 * MB);  // 4 MB
  unsigned short* Sc = (unsigned short*)(ws + 22 * MB);  // 4 MB (bf16 chunk sums)
  unsigned short* Sp = (unsigned short*)(ws + 26 * MB);  // 4 MB (bf16 exclusive prefix)
  float*          zc = (float*)(ws + 30 * MB);           // 128 KB
  float*          zp = (float*)(ws + 30 * MB + 131072);  // 128 KB

  k_prep_inputs<<<dim3(5120), dim3(256), 0, stream>>>(x, xb, W, Wt);
  k_gemm_fused<<<dim3(16, 16), dim3(768), 0, stream>>>(xb, Wt, b, qh, kh, vt, Sc, zc);
  k_scan<<<dim3(257), dim3(256), 0, stream>>>(Sc, Sp, zc, zp);
  k_attn<<<dim3(512), dim3(256), 0, stream>>>(qh, kh, vt, Sp, zp, (float*)d_out);
}